// Round 8
// baseline (44.421 us; speedup 1.0000x reference)
//
#include <hip/hip_runtime.h>

#define B 16
#define F_DIM 256
#define P 8192
#define C 96
#define H 256
#define NSEG (B * C)          // 1536
#define G 8                   // feature rows per pool block
#define NFBLK (F_DIM / G)     // 32
#define SPLIT 4               // P split factor
#define PQ (P / SPLIT)        // 2048 points per block

// order-preserving float <-> uint mapping for atomicMax-based float max
__device__ __forceinline__ unsigned f2key(float x) {
    unsigned u = __float_as_uint(x);
    return (u & 0x80000000u) ? ~u : (u | 0x80000000u);
}
__device__ __forceinline__ float key2f(unsigned k) {
    unsigned u = (k & 0x80000000u) ? (k & 0x7FFFFFFFu) : ~k;
    return __uint_as_float(u);
}

// block = (batch b, feature group fg, P-quarter q). Writes RAW uint partial
// max-keys to kbuf[q]; counts per quarter from fg==0 blocks. No global atomics.
__global__ __launch_bounds__(256) void pool_kernel(const float* __restrict__ feat,
                                                   const int* __restrict__ label,
                                                   unsigned* __restrict__ kbuf,
                                                   int* __restrict__ cnts) {
    __shared__ unsigned smax[G][C];
    __shared__ int hist[C];
    const int blk = blockIdx.x;
    const int q  = blk & 3;            // P-quarter
    const int fg = (blk >> 2) & 31;    // feature group
    const int b  = blk >> 7;           // batch
    const int f0 = fg << 3;
    const int t = threadIdx.x;

    for (int i = t; i < G * C; i += 256) ((unsigned*)smax)[i] = 0u;  // key identity
    if (t < C) hist[t] = 0;
    __syncthreads();

    // this thread's 8 labels of the quarter (2 int4), loaded once
    const int4* lrow4 = (const int4*)(label + (size_t)b * P + (size_t)q * PQ);
    int4 lab[2];
    lab[0] = lrow4[t];
    lab[1] = lrow4[t + 256];

    if (fg == 0) {   // one fg per (b,q) computes the quarter-histogram
        #pragma unroll
        for (int j = 0; j < 2; ++j) {
            atomicAdd(&hist[lab[j].x], 1);
            atomicAdd(&hist[lab[j].y], 1);
            atomicAdd(&hist[lab[j].z], 1);
            atomicAdd(&hist[lab[j].w], 1);
        }
    }

    const float4* fbase4 = (const float4*)(feat + ((size_t)b * F_DIM + f0) * P + (size_t)q * PQ);

    // 8 feature-row phases, 1-deep prefetch
    float4 cur[2], nxt[2];
    cur[0] = fbase4[t];
    cur[1] = fbase4[t + 256];

    #pragma unroll 1
    for (int f = 0; f < G; ++f) {
        if (f + 1 < G) {
            nxt[0] = fbase4[(size_t)(f + 1) * (P / 4) + t];
            nxt[1] = fbase4[(size_t)(f + 1) * (P / 4) + t + 256];
        }
        #pragma unroll
        for (int j = 0; j < 2; ++j) {
            atomicMax(&smax[f][lab[j].x], f2key(cur[j].x));
            atomicMax(&smax[f][lab[j].y], f2key(cur[j].y));
            atomicMax(&smax[f][lab[j].z], f2key(cur[j].z));
            atomicMax(&smax[f][lab[j].w], f2key(cur[j].w));
        }
        cur[0] = nxt[0];
        cur[1] = nxt[1];
    }
    __syncthreads();

    if (fg == 0 && t < C) cnts[q * NSEG + b * C + t] = hist[t];

    // epilogue: thread t < 96 owns class t, writes 8 raw keys (2 uint4)
    if (t < C) {
        uint4 lo, hi;
        lo.x = smax[0][t]; lo.y = smax[1][t]; lo.z = smax[2][t]; lo.w = smax[3][t];
        hi.x = smax[4][t]; hi.y = smax[5][t]; hi.z = smax[6][t]; hi.w = smax[7][t];
        unsigned* dst = kbuf + (size_t)q * NSEG * F_DIM + (size_t)(b * C + t) * F_DIM + f0;
        *(uint4*)dst = lo;
        *(uint4*)(dst + 4) = hi;
    }
}

// dense layer: y = (relu?)(x @ w + bias). POOLIN: x is materialized on the fly
// from 4 partial key buffers + quarter counts (merge fused into staging).
// block: 8 rows x COLS cols; 256 threads = 16 col-quads x 16 k-slices (split-K).
template <int COLS, int RELU, int OUTW, int POOLIN>
__global__ __launch_bounds__(256, 3) void dense_kernel(const float* __restrict__ x,
                                                       const unsigned* __restrict__ kx,
                                                       const int* __restrict__ cnts,
                                                       const float* __restrict__ w,
                                                       const float* __restrict__ bias,
                                                       float* __restrict__ y,
                                                       float* __restrict__ tails) {
    constexpr int NQ = COLS / 4;       // active col-quads (<= 16)
    __shared__ float xs[8][H];
    __shared__ float ps[8][COLS][17];  // [row][col][slice], padded
    const int t = threadIdx.x;
    const int row0 = blockIdx.x * 8;
    const int bj0 = blockIdx.y * COLS;

    // stage 8 rows of x (512 float4), coalesced
    if (POOLIN) {
        const uint4* k4 = (const uint4*)kx;
        const size_t base = (size_t)row0 * (H / 4);
        #pragma unroll
        for (int jj = 0; jj < 2; ++jj) {
            const int i = t + jj * 256;
            uint4 km = k4[base + i];
            #pragma unroll
            for (int h = 1; h < SPLIT; ++h) {
                const uint4 kh = k4[(size_t)h * NSEG * (H / 4) + base + i];
                km.x = km.x > kh.x ? km.x : kh.x;
                km.y = km.y > kh.y ? km.y : kh.y;
                km.z = km.z > kh.z ? km.z : kh.z;
                km.w = km.w > kh.w ? km.w : kh.w;
            }
            const int row = row0 + (i >> 6);
            const int cnt = cnts[row] + cnts[NSEG + row] +
                            cnts[2 * NSEG + row] + cnts[3 * NSEG + row];
            float4 v;
            v.x = key2f(km.x); v.y = key2f(km.y); v.z = key2f(km.z); v.w = key2f(km.w);
            if (cnt == 0) {
                v.x = v.y = v.z = v.w = 0.0f;
            } else if (cnt != P) {
                v.x = fmaxf(v.x, 0.0f); v.y = fmaxf(v.y, 0.0f);
                v.z = fmaxf(v.z, 0.0f); v.w = fmaxf(v.w, 0.0f);
            }
            ((float4*)xs)[i] = v;
        }
    } else {
        int i0 = t, i1 = t + 256;
        ((float4*)xs)[i0] = ((const float4*)(x + (size_t)row0 * H))[i0];
        ((float4*)xs)[i1] = ((const float4*)(x + (size_t)row0 * H))[i1];
    }
    __syncthreads();

    const int s = t >> 4;     // k-slice 0..15
    const int jq = t & 15;    // col-quad

    if (jq < NQ) {
        const float4* w4 = (const float4*)w;
        constexpr int WS4 = OUTW / 4;   // float4 per weight row
        const int wq = (bj0 >> 2) + jq;
        const int kbase = s * 16;
        float4 acc[8];
        #pragma unroll
        for (int r = 0; r < 8; ++r) acc[r] = (float4){0.f, 0.f, 0.f, 0.f};

        #pragma unroll
        for (int i = 0; i < 16; ++i) {
            const int k = kbase + i;
            const float4 wv = w4[k * WS4 + wq];
            #pragma unroll
            for (int r = 0; r < 8; ++r) {
                const float xv = xs[r][k];
                acc[r].x = fmaf(xv, wv.x, acc[r].x);
                acc[r].y = fmaf(xv, wv.y, acc[r].y);
                acc[r].z = fmaf(xv, wv.z, acc[r].z);
                acc[r].w = fmaf(xv, wv.w, acc[r].w);
            }
        }
        #pragma unroll
        for (int r = 0; r < 8; ++r) {
            ps[r][jq * 4 + 0][s] = acc[r].x;
            ps[r][jq * 4 + 1][s] = acc[r].y;
            ps[r][jq * 4 + 2][s] = acc[r].z;
            ps[r][jq * 4 + 3][s] = acc[r].w;
        }
    }
    __syncthreads();

    // reduce 16 slices + bias (+relu), write out
    for (int e = t; e < 8 * COLS; e += 256) {
        const int r = e / COLS, j = e % COLS;
        float v = bias[bj0 + j];
        #pragma unroll
        for (int q = 0; q < 16; ++q) v += ps[r][j][q];
        if (RELU) v = fmaxf(v, 0.0f);
        y[(size_t)(row0 + r) * OUTW + bj0 + j] = v;
    }

    // part_label / part_batch tails (only last layer passes tails != null)
    if (tails != nullptr && t < 8) {
        const int row = row0 + t;
        tails[row] = (float)(row % C);
        tails[NSEG + row] = (float)(row / C);
    }
}

extern "C" void kernel_launch(void* const* d_in, const int* in_sizes, int n_in,
                              void* d_out, int out_size, void* d_ws, size_t ws_size,
                              hipStream_t stream) {
    const float* feat  = (const float*)d_in[0];
    const int*   label = (const int*)d_in[1];
    const float* w1    = (const float*)d_in[2];
    const float* b1    = (const float*)d_in[3];
    const float* w2    = (const float*)d_in[4];
    const float* b2    = (const float*)d_in[5];
    const float* wl    = (const float*)d_in[6];
    const float* bl    = (const float*)d_in[7];
    float* out = (float*)d_out;

    char* ws = (char*)d_ws;
    const size_t KBYTES = (size_t)SPLIT * NSEG * H * 4;   // 6 MB partial keys
    unsigned* kbuf = (unsigned*)ws;
    int*      cnts = (int*)(ws + KBYTES);                 // 24 KB
    float*    h1   = (float*)(ws + KBYTES + 32768);       // 1.5 MB
    float*    h2   = (float*)(ws + KBYTES + 32768 + (size_t)NSEG * H * 4);

    pool_kernel<<<B * NFBLK * SPLIT, 256, 0, stream>>>(feat, label, kbuf, cnts);
    dense_kernel<64, 1, H, 1><<<dim3(NSEG / 8, 4), 256, 0, stream>>>(nullptr, kbuf, cnts, w1, b1, h1, nullptr);
    dense_kernel<64, 1, H, 0><<<dim3(NSEG / 8, 4), 256, 0, stream>>>(h1, nullptr, nullptr, w2, b2, h2, nullptr);
    dense_kernel<48, 0, C, 0><<<dim3(NSEG / 8, 2), 256, 0, stream>>>(h2, nullptr, nullptr, wl, bl, out, out + (size_t)NSEG * C);
}

// Round 9
// 44.402 us; speedup vs baseline: 1.0004x; 1.0004x over previous
//
#include <hip/hip_runtime.h>

#define B 16
#define F_DIM 256
#define P 8192
#define C 96
#define H 256
#define NSEG (B * C)          // 1536
#define G 8                   // feature rows per pool block
#define NFBLK (F_DIM / G)     // 32
#define SPLIT 4               // P split factor
#define PQ (P / SPLIT)        // 2048 points per block

// Signed-int max on raw float bits == float max whenever true max >= 0.
// All-negative buckets return a negative value; every cnt!=P bucket gets
// relu() in the epilogue, so the result is still exact. Seed INT_MIN = -0.0f.

// block = (batch b, feature group fg, P-quarter q). Writes RAW int-bit partial
// max to kbuf[q]; counts per quarter from fg==0 blocks. No global atomics,
// no per-element VALU transform: 1 ds_max_i32 per element.
__global__ __launch_bounds__(256) void pool_kernel(const float* __restrict__ feat,
                                                   const int* __restrict__ label,
                                                   int* __restrict__ kbuf,
                                                   int* __restrict__ cnts) {
    __shared__ int smax[G][C];
    __shared__ int hist[C];
    const int blk = blockIdx.x;
    const int q  = blk & 3;            // P-quarter
    const int fg = (blk >> 2) & 31;    // feature group
    const int b  = blk >> 7;           // batch
    const int f0 = fg << 3;
    const int t = threadIdx.x;

    for (int i = t; i < G * C; i += 256) ((int*)smax)[i] = 0x80000000;  // -0.0f
    if (t < C) hist[t] = 0;
    __syncthreads();

    // this thread's 8 labels of the quarter (2 int4), loaded once
    const int4* lrow4 = (const int4*)(label + (size_t)b * P + (size_t)q * PQ);
    int4 lab[2];
    lab[0] = lrow4[t];
    lab[1] = lrow4[t + 256];

    if (fg == 0) {   // one fg per (b,q) computes the quarter-histogram
        #pragma unroll
        for (int j = 0; j < 2; ++j) {
            atomicAdd(&hist[lab[j].x], 1);
            atomicAdd(&hist[lab[j].y], 1);
            atomicAdd(&hist[lab[j].z], 1);
            atomicAdd(&hist[lab[j].w], 1);
        }
    }

    const float4* fbase4 = (const float4*)(feat + ((size_t)b * F_DIM + f0) * P + (size_t)q * PQ);

    // 8 feature-row phases, fully unrolled (immediate LDS offsets), 1-deep prefetch
    float4 cur[2], nxt[2];
    cur[0] = fbase4[t];
    cur[1] = fbase4[t + 256];

    #pragma unroll
    for (int f = 0; f < G; ++f) {
        if (f + 1 < G) {
            nxt[0] = fbase4[(size_t)(f + 1) * (P / 4) + t];
            nxt[1] = fbase4[(size_t)(f + 1) * (P / 4) + t + 256];
        }
        #pragma unroll
        for (int j = 0; j < 2; ++j) {
            atomicMax(&smax[f][lab[j].x], __float_as_int(cur[j].x));
            atomicMax(&smax[f][lab[j].y], __float_as_int(cur[j].y));
            atomicMax(&smax[f][lab[j].z], __float_as_int(cur[j].z));
            atomicMax(&smax[f][lab[j].w], __float_as_int(cur[j].w));
        }
        cur[0] = nxt[0];
        cur[1] = nxt[1];
    }
    __syncthreads();

    if (fg == 0 && t < C) cnts[q * NSEG + b * C + t] = hist[t];

    // epilogue: thread t < 96 owns class t, writes 8 raw int maxes (2 int4)
    if (t < C) {
        int4 lo, hi;
        lo.x = smax[0][t]; lo.y = smax[1][t]; lo.z = smax[2][t]; lo.w = smax[3][t];
        hi.x = smax[4][t]; hi.y = smax[5][t]; hi.z = smax[6][t]; hi.w = smax[7][t];
        int* dst = kbuf + (size_t)q * NSEG * F_DIM + (size_t)(b * C + t) * F_DIM + f0;
        *(int4*)dst = lo;
        *(int4*)(dst + 4) = hi;
    }
}

// dense layer: y = (relu?)(x @ w + bias). POOLIN: x is materialized on the fly
// from 4 partial int-bit buffers + quarter counts (signed-int merge, relu rule).
// block: 8 rows x COLS cols; 256 threads = 16 col-quads x 16 k-slices (split-K).
template <int COLS, int RELU, int OUTW, int POOLIN>
__global__ __launch_bounds__(256, 3) void dense_kernel(const float* __restrict__ x,
                                                       const int* __restrict__ kx,
                                                       const int* __restrict__ cnts,
                                                       const float* __restrict__ w,
                                                       const float* __restrict__ bias,
                                                       float* __restrict__ y,
                                                       float* __restrict__ tails) {
    constexpr int NQ = COLS / 4;       // active col-quads (<= 16)
    __shared__ float xs[8][H];
    __shared__ float ps[8][COLS][17];  // [row][col][slice], padded
    const int t = threadIdx.x;
    const int row0 = blockIdx.x * 8;
    const int bj0 = blockIdx.y * COLS;

    // stage 8 rows of x (512 float4), coalesced
    if (POOLIN) {
        const int4* k4 = (const int4*)kx;
        const size_t base = (size_t)row0 * (H / 4);
        #pragma unroll
        for (int jj = 0; jj < 2; ++jj) {
            const int i = t + jj * 256;
            int4 km = k4[base + i];
            #pragma unroll
            for (int h = 1; h < SPLIT; ++h) {
                const int4 kh = k4[(size_t)h * NSEG * (H / 4) + base + i];
                km.x = km.x > kh.x ? km.x : kh.x;
                km.y = km.y > kh.y ? km.y : kh.y;
                km.z = km.z > kh.z ? km.z : kh.z;
                km.w = km.w > kh.w ? km.w : kh.w;
            }
            const int row = row0 + (i >> 6);
            const int cnt = cnts[row] + cnts[NSEG + row] +
                            cnts[2 * NSEG + row] + cnts[3 * NSEG + row];
            float4 v;
            v.x = __int_as_float(km.x); v.y = __int_as_float(km.y);
            v.z = __int_as_float(km.z); v.w = __int_as_float(km.w);
            if (cnt == 0) {
                v.x = v.y = v.z = v.w = 0.0f;
            } else if (cnt != P) {
                v.x = fmaxf(v.x, 0.0f); v.y = fmaxf(v.y, 0.0f);
                v.z = fmaxf(v.z, 0.0f); v.w = fmaxf(v.w, 0.0f);
            }
            ((float4*)xs)[i] = v;
        }
    } else {
        int i0 = t, i1 = t + 256;
        ((float4*)xs)[i0] = ((const float4*)(x + (size_t)row0 * H))[i0];
        ((float4*)xs)[i1] = ((const float4*)(x + (size_t)row0 * H))[i1];
    }
    __syncthreads();

    const int s = t >> 4;     // k-slice 0..15
    const int jq = t & 15;    // col-quad

    if (jq < NQ) {
        const float4* w4 = (const float4*)w;
        constexpr int WS4 = OUTW / 4;   // float4 per weight row
        const int wq = (bj0 >> 2) + jq;
        const int kbase = s * 16;
        float4 acc[8];
        #pragma unroll
        for (int r = 0; r < 8; ++r) acc[r] = (float4){0.f, 0.f, 0.f, 0.f};

        #pragma unroll
        for (int i = 0; i < 16; ++i) {
            const int k = kbase + i;
            const float4 wv = w4[k * WS4 + wq];
            #pragma unroll
            for (int r = 0; r < 8; ++r) {
                const float xv = xs[r][k];
                acc[r].x = fmaf(xv, wv.x, acc[r].x);
                acc[r].y = fmaf(xv, wv.y, acc[r].y);
                acc[r].z = fmaf(xv, wv.z, acc[r].z);
                acc[r].w = fmaf(xv, wv.w, acc[r].w);
            }
        }
        #pragma unroll
        for (int r = 0; r < 8; ++r) {
            ps[r][jq * 4 + 0][s] = acc[r].x;
            ps[r][jq * 4 + 1][s] = acc[r].y;
            ps[r][jq * 4 + 2][s] = acc[r].z;
            ps[r][jq * 4 + 3][s] = acc[r].w;
        }
    }
    __syncthreads();

    // reduce 16 slices + bias (+relu), write out
    for (int e = t; e < 8 * COLS; e += 256) {
        const int r = e / COLS, j = e % COLS;
        float v = bias[bj0 + j];
        #pragma unroll
        for (int q = 0; q < 16; ++q) v += ps[r][j][q];
        if (RELU) v = fmaxf(v, 0.0f);
        y[(size_t)(row0 + r) * OUTW + bj0 + j] = v;
    }

    // part_label / part_batch tails (only last layer passes tails != null)
    if (tails != nullptr && t < 8) {
        const int row = row0 + t;
        tails[row] = (float)(row % C);
        tails[NSEG + row] = (float)(row / C);
    }
}

extern "C" void kernel_launch(void* const* d_in, const int* in_sizes, int n_in,
                              void* d_out, int out_size, void* d_ws, size_t ws_size,
                              hipStream_t stream) {
    const float* feat  = (const float*)d_in[0];
    const int*   label = (const int*)d_in[1];
    const float* w1    = (const float*)d_in[2];
    const float* b1    = (const float*)d_in[3];
    const float* w2    = (const float*)d_in[4];
    const float* b2    = (const float*)d_in[5];
    const float* wl    = (const float*)d_in[6];
    const float* bl    = (const float*)d_in[7];
    float* out = (float*)d_out;

    char* ws = (char*)d_ws;
    const size_t KBYTES = (size_t)SPLIT * NSEG * H * 4;   // 6 MB partial keys
    int*   kbuf = (int*)ws;
    int*   cnts = (int*)(ws + KBYTES);                    // 24 KB
    float* h1   = (float*)(ws + KBYTES + 32768);          // 1.5 MB
    float* h2   = (float*)(ws + KBYTES + 32768 + (size_t)NSEG * H * 4);

    pool_kernel<<<B * NFBLK * SPLIT, 256, 0, stream>>>(feat, label, kbuf, cnts);
    dense_kernel<64, 1, H, 1><<<dim3(NSEG / 8, 4), 256, 0, stream>>>(nullptr, kbuf, cnts, w1, b1, h1, nullptr);
    dense_kernel<64, 1, H, 0><<<dim3(NSEG / 8, 4), 256, 0, stream>>>(h1, nullptr, nullptr, w2, b2, h2, nullptr);
    dense_kernel<48, 0, C, 0><<<dim3(NSEG / 8, 2), 256, 0, stream>>>(h2, nullptr, nullptr, wl, bl, out, out + (size_t)NSEG * C);
}